// Round 1
// baseline (12839.679 us; speedup 1.0000x reference)
//
#include <hip/hip_runtime.h>
#include <hip/hip_bf16.h>
#include <cstdint>
#include <cstddef>

// GRU: T=512, B=64, I=256, H=1024, O=256, L=3
#define TT 512
#define BB 64
#define II 256
#define HH 1024
#define OO 256
#define LL 3

typedef _Float16 half8 __attribute__((ext_vector_type(8)));
typedef float floatx4 __attribute__((ext_vector_type(4)));

struct StepArgs {
    const _Float16* x16;      // [T][B][I]
    _Float16* y16[3];         // [T][B][H] each (layer outputs, fp16)
    const _Float16* wih[3];   // [3H][Kin]
    const _Float16* whh[3];   // [3H][H]
    const float* bih[3];      // [3H]
    const float* bhh[3];      // [3H]
    float* h32;               // [L][2][B][H] fp32 master state (parity dbuf)
    _Float16* h16;            // [L][2][B][H] fp16 shadow for MFMA
    float* out_h;             // d_out + T*B*O  -> [L][B][H]
};

__global__ void cast_f32_f16(const float* __restrict__ in, _Float16* __restrict__ out, int n) {
    int i = blockIdx.x * 256 + threadIdx.x;
    if (i < n) out[i] = (_Float16)in[i];
}

__global__ void init_h(const float* __restrict__ h0, float* __restrict__ h32,
                       _Float16* __restrict__ h16) {
    int i = blockIdx.x * 256 + threadIdx.x;
    if (i >= LL * BB * HH) return;
    int l = i / (BB * HH);
    int rest = i - l * (BB * HH);
    float v = h0[i];
    size_t b0 = ((size_t)l * 2 + 0) * BB * HH + rest;
    size_t b1 = ((size_t)l * 2 + 1) * BB * HH + rest;
    h32[b0] = v; h32[b1] = v;
    h16[b0] = (_Float16)v; h16[b1] = (_Float16)v;
}

// One superstep: layer l processes t = s - l (pipelined).
// Grid: 768 blocks x 64 threads. block = (layer, mb in 0..3, jb in 0..63).
// Each wave: 16 B-rows x 16 hidden-units tile, all 3 gates, K over (Kin + H).
__global__ __launch_bounds__(64) void gru_step(StepArgs a, int s) {
    const int wg = blockIdx.x;
    const int layer = wg >> 8;
    const int t = s - layer;
    if (t < 0 || t >= TT) return;
    const int r = wg & 255;
    const int mb = r >> 6;        // B-row block (16 rows)
    const int jb = r & 63;        // hidden-unit block (16 units)
    const int lane = threadIdx.x;
    const int lr = lane & 15;
    const int lk = (lane >> 4) << 3;   // 8 contiguous k per lane quarter

    const int Kin = (layer == 0) ? II : HH;
    const _Float16* Ain = (layer == 0)
        ? (a.x16 + (size_t)t * BB * II)
        : (a.y16[layer - 1] + (size_t)t * BB * HH);
    const int par = s & 1;
    const _Float16* Ah = a.h16 + ((size_t)(layer * 2 + par)) * BB * HH;

    const int j = jb * 16 + lr;       // this lane's weight row (per gate)
    const int browbase = mb * 16;

    floatx4 acc_r{0.f,0.f,0.f,0.f}, acc_z{0.f,0.f,0.f,0.f};
    floatx4 acc_in{0.f,0.f,0.f,0.f}, acc_hn{0.f,0.f,0.f,0.f};

    // input-side projection gi (fused): K = Kin
    {
        const _Float16* Ar = Ain + (size_t)(browbase + lr) * Kin + lk;
        const _Float16* Wr = a.wih[layer] + (size_t)(0 * HH + j) * Kin + lk;
        const _Float16* Wz = a.wih[layer] + (size_t)(1 * HH + j) * Kin + lk;
        const _Float16* Wn = a.wih[layer] + (size_t)(2 * HH + j) * Kin + lk;
        for (int k = 0; k < Kin; k += 32) {
            half8 av = *(const half8*)(Ar + k);
            acc_r  = __builtin_amdgcn_mfma_f32_16x16x32_f16(av, *(const half8*)(Wr + k), acc_r,  0, 0, 0);
            acc_z  = __builtin_amdgcn_mfma_f32_16x16x32_f16(av, *(const half8*)(Wz + k), acc_z,  0, 0, 0);
            acc_in = __builtin_amdgcn_mfma_f32_16x16x32_f16(av, *(const half8*)(Wn + k), acc_in, 0, 0, 0);
        }
    }
    // hidden-side projection gh: K = H
    {
        const _Float16* Ar = Ah + (size_t)(browbase + lr) * HH + lk;
        const _Float16* Wr = a.whh[layer] + (size_t)(0 * HH + j) * HH + lk;
        const _Float16* Wz = a.whh[layer] + (size_t)(1 * HH + j) * HH + lk;
        const _Float16* Wn = a.whh[layer] + (size_t)(2 * HH + j) * HH + lk;
        for (int k = 0; k < HH; k += 32) {
            half8 av = *(const half8*)(Ar + k);
            acc_r  = __builtin_amdgcn_mfma_f32_16x16x32_f16(av, *(const half8*)(Wr + k), acc_r,  0, 0, 0);
            acc_z  = __builtin_amdgcn_mfma_f32_16x16x32_f16(av, *(const half8*)(Wz + k), acc_z,  0, 0, 0);
            acc_hn = __builtin_amdgcn_mfma_f32_16x16x32_f16(av, *(const half8*)(Wn + k), acc_hn, 0, 0, 0);
        }
    }

    // epilogue: gates + state update. n-gate: b_hh_n sits INSIDE r*(...)
    const float bir = a.bih[layer][j],          bhr = a.bhh[layer][j];
    const float biz = a.bih[layer][HH + j],     bhz = a.bhh[layer][HH + j];
    const float bin = a.bih[layer][2 * HH + j], bhn = a.bhh[layer][2 * HH + j];
    const float* h32o = a.h32 + ((size_t)(layer * 2 + par)) * BB * HH;
    float*   h32n = a.h32 + ((size_t)(layer * 2 + (par ^ 1))) * BB * HH;
    _Float16* h16n = a.h16 + ((size_t)(layer * 2 + (par ^ 1))) * BB * HH;
    _Float16* yo = a.y16[layer] + (size_t)t * BB * HH;

#pragma unroll
    for (int i = 0; i < 4; ++i) {
        int brow = browbase + (lane >> 4) * 4 + i;   // C/D: row=(lane>>4)*4+i, col=lane&15
        float rg = 1.f / (1.f + expf(-(acc_r[i] + bir + bhr)));
        float zg = 1.f / (1.f + expf(-(acc_z[i] + biz + bhz)));
        float ng = tanhf(acc_in[i] + bin + rg * (acc_hn[i] + bhn));
        float hold = h32o[(size_t)brow * HH + j];
        float hnew = (1.f - zg) * ng + zg * hold;
        h32n[(size_t)brow * HH + j] = hnew;
        h16n[(size_t)brow * HH + j] = (_Float16)hnew;
        yo[(size_t)brow * HH + j] = (_Float16)hnew;
        if (t == TT - 1) a.out_h[((size_t)layer * BB + brow) * HH + j] = hnew;
    }
}

// y = y_l2 @ fc_w^T + fc_b. M=T*B=32768, N=256, K=1024. 1 wave per 16x16 tile.
__global__ __launch_bounds__(256) void fc_kernel(const _Float16* __restrict__ y,
                                                 const _Float16* __restrict__ w,
                                                 const float* __restrict__ bias,
                                                 float* __restrict__ out) {
    const int wid = (blockIdx.x << 2) + (threadIdx.x >> 6);
    const int lane = threadIdx.x & 63;
    const int mt = wid >> 4;          // 0..2047
    const int nt = wid & 15;          // 0..15
    const int lr = lane & 15;
    const int lk = (lane >> 4) << 3;
    const _Float16* Ar = y + (size_t)(mt * 16 + lr) * HH + lk;
    const _Float16* Br = w + (size_t)(nt * 16 + lr) * HH + lk;
    floatx4 acc{0.f,0.f,0.f,0.f};
    for (int k = 0; k < HH; k += 32)
        acc = __builtin_amdgcn_mfma_f32_16x16x32_f16(*(const half8*)(Ar + k),
                                                     *(const half8*)(Br + k), acc, 0, 0, 0);
    const float b = bias[nt * 16 + lr];
#pragma unroll
    for (int i = 0; i < 4; ++i)
        out[(size_t)(mt * 16 + (lane >> 4) * 4 + i) * OO + nt * 16 + lr] = acc[i] + b;
}

extern "C" void kernel_launch(void* const* d_in, const int* in_sizes, int n_in,
                              void* d_out, int out_size, void* d_ws, size_t ws_size,
                              hipStream_t stream) {
    const float* x    = (const float*)d_in[0];
    const float* h0   = (const float*)d_in[1];
    const float* fc_w = (const float*)d_in[2];
    const float* fc_b = (const float*)d_in[3];
    const float* wih[3]; const float* whh[3]; const float* bih[3]; const float* bhh[3];
    for (int l = 0; l < 3; ++l) {
        wih[l] = (const float*)d_in[4 + l * 4 + 0];
        whh[l] = (const float*)d_in[4 + l * 4 + 1];
        bih[l] = (const float*)d_in[4 + l * 4 + 2];
        bhh[l] = (const float*)d_in[4 + l * 4 + 3];
    }

    // ---- carve workspace (all fp16 shadows + state) ----
    char* p = (char*)d_ws;
    auto alloc = [&](size_t bytes) {
        char* q = p;
        p += (bytes + 255) & ~(size_t)255;
        return q;
    };
    _Float16* x16 = (_Float16*)alloc((size_t)TT * BB * II * 2);
    _Float16* y16[3];
    for (int l = 0; l < 3; ++l) y16[l] = (_Float16*)alloc((size_t)TT * BB * HH * 2);
    _Float16* wih16[3];
    wih16[0] = (_Float16*)alloc((size_t)3 * HH * II * 2);
    wih16[1] = (_Float16*)alloc((size_t)3 * HH * HH * 2);
    wih16[2] = (_Float16*)alloc((size_t)3 * HH * HH * 2);
    _Float16* whh16[3];
    for (int l = 0; l < 3; ++l) whh16[l] = (_Float16*)alloc((size_t)3 * HH * HH * 2);
    _Float16* fcw16 = (_Float16*)alloc((size_t)OO * HH * 2);
    float* h32 = (float*)alloc((size_t)LL * 2 * BB * HH * 4);
    _Float16* h16 = (_Float16*)alloc((size_t)LL * 2 * BB * HH * 2);
    if ((size_t)(p - (char*)d_ws) > ws_size) return;  // ws too small: fail loudly

    // ---- fp16 casts (re-done every call; deterministic) ----
    auto cast = [&](const float* src, _Float16* dst, int n) {
        cast_f32_f16<<<(n + 255) / 256, 256, 0, stream>>>(src, dst, n);
    };
    cast(x, x16, TT * BB * II);
    cast(wih[0], wih16[0], 3 * HH * II);
    cast(wih[1], wih16[1], 3 * HH * HH);
    cast(wih[2], wih16[2], 3 * HH * HH);
    for (int l = 0; l < 3; ++l) cast(whh[l], whh16[l], 3 * HH * HH);
    cast(fc_w, fcw16, OO * HH);
    init_h<<<(LL * BB * HH + 255) / 256, 256, 0, stream>>>(h0, h32, h16);

    // ---- pipelined recurrent supersteps ----
    StepArgs a;
    a.x16 = x16;
    for (int l = 0; l < 3; ++l) {
        a.y16[l] = y16[l];
        a.wih[l] = wih16[l];
        a.whh[l] = whh16[l];
        a.bih[l] = bih[l];
        a.bhh[l] = bhh[l];
    }
    a.h32 = h32;
    a.h16 = h16;
    a.out_h = (float*)d_out + (size_t)TT * BB * OO;

    for (int s = 0; s < TT + LL - 1; ++s)
        gru_step<<<768, 64, 0, stream>>>(a, s);

    // ---- final FC ----
    fc_kernel<<<(TT * BB / 16) * (OO / 16) / 4, 256, 0, stream>>>(
        y16[2], fcw16, fc_b, (float*)d_out);
}